// Round 1
// baseline (2774.625 us; speedup 1.0000x reference)
//
#include <hip/hip_runtime.h>
#include <hip/hip_bf16.h>
#include <cstdint>
#include <cmath>

// Problem constants
#define BATCH 32
#define CH 64
#define HW 64
#define NPIX 4096          // 64*64
#define NEXP 4             // local experts per branch
#define DFLAT 262144       // C*H*W
#define PSTRIDE 68         // padded LDS plane row stride (16B aligned)

static __device__ __forceinline__ float lrelu(float v) {
    return v > 0.f ? v : 0.2f * v;
}

// ---------------------------------------------------------------------------
// Gating: one block per (branch, sample). 256 threads reduce 8 dot products
// (4 gate cols + 4 noise cols) over D=262144, then thread 0 does softplus,
// noisy logits, top-2, softmax -> sel[2][32][2], gv[2][32][2].
// ---------------------------------------------------------------------------
__global__ __launch_bounds__(256) void gating_kernel(
    const float* __restrict__ x_rgb, const float* __restrict__ x_ir,
    const float* __restrict__ n_rgb, const float* __restrict__ n_ir,
    const float* __restrict__ wg_rgb, const float* __restrict__ wn_rgb,
    const float* __restrict__ wg_ir,  const float* __restrict__ wn_ir,
    int* __restrict__ sel, float* __restrict__ gv)
{
    const int br = blockIdx.x >> 5;
    const int b  = blockIdx.x & 31;
    const float*  x  = (br ? x_ir : x_rgb) + (size_t)b * DFLAT;
    const float4* wg = (const float4*)(br ? wg_ir : wg_rgb);
    const float4* wn = (const float4*)(br ? wn_ir : wn_rgb);
    const float*  nz = (br ? n_ir : n_rgb) + b * NEXP;
    const int t = threadIdx.x;

    float cg0=0.f,cg1=0.f,cg2=0.f,cg3=0.f;
    float cn0=0.f,cn1=0.f,cn2=0.f,cn3=0.f;
    for (int i = 0; i < DFLAT/256; ++i) {
        const int d = (i << 8) + t;
        const float  xv = x[d];
        const float4 g4 = wg[d];
        const float4 n4 = wn[d];
        cg0 = fmaf(xv, g4.x, cg0); cg1 = fmaf(xv, g4.y, cg1);
        cg2 = fmaf(xv, g4.z, cg2); cg3 = fmaf(xv, g4.w, cg3);
        cn0 = fmaf(xv, n4.x, cn0); cn1 = fmaf(xv, n4.y, cn1);
        cn2 = fmaf(xv, n4.z, cn2); cn3 = fmaf(xv, n4.w, cn3);
    }

    __shared__ float red[8][256];
    red[0][t]=cg0; red[1][t]=cg1; red[2][t]=cg2; red[3][t]=cg3;
    red[4][t]=cn0; red[5][t]=cn1; red[6][t]=cn2; red[7][t]=cn3;
    __syncthreads();
    for (int s = 128; s > 0; s >>= 1) {
        if (t < s) {
            #pragma unroll
            for (int v = 0; v < 8; ++v) red[v][t] += red[v][t + s];
        }
        __syncthreads();
    }

    if (t == 0) {
        float logit[4];
        #pragma unroll
        for (int e = 0; e < 4; ++e) {
            const float clean = red[e][0];
            const float zz    = red[4 + e][0];
            const float sp    = fmaxf(zz, 0.f) + log1pf(expf(-fabsf(zz)));
            logit[e] = clean + nz[e] * (sp + 1e-2f);
        }
        int i1 = 0;
        #pragma unroll
        for (int e = 1; e < 4; ++e) if (logit[e] > logit[i1]) i1 = e;
        int i2 = (i1 == 0) ? 1 : 0;
        #pragma unroll
        for (int e = 0; e < 4; ++e)
            if (e != i1 && logit[e] > logit[i2]) i2 = e;
        const float ex = expf(logit[i2] - logit[i1]);
        const float s  = 1.f + ex;
        const int base = (br * 32 + b) * 2;
        sel[base]     = i1;
        sel[base + 1] = i2;
        gv[base]      = 1.f / s;
        gv[base + 1]  = ex / s;
    }
}

// ---------------------------------------------------------------------------
// conv1: per selected expert, h = leaky_relu(conv3x3(x, We1[e]) + be1[e]).
// grid (slot=64, ocg=8, half=2), 256 threads. Each block: 8 oc x 32 rows.
// Thread patch: 2 rows x 4 cols. Input plane staged padded in LDS.
// ---------------------------------------------------------------------------
__global__ __launch_bounds__(256) void conv1_kernel(
    const float* __restrict__ x,      // [32][64][4096] (branch input)
    const int* __restrict__ sel,      // [2][32][2]
    const float* __restrict__ We1,    // [8][64][64][9]
    const float* __restrict__ be1,    // [8][64]
    float* __restrict__ h,            // [64][64][4096] (branch-local slots)
    int branch)
{
    const int slot = blockIdx.x;           // b*2+k
    const int b    = slot >> 1;
    const int k    = slot & 1;
    const int ocb  = blockIdx.y * 8;
    const int z    = blockIdx.z;           // row half
    const int t    = threadIdx.x;

    const int e    = sel[(branch * 32 + b) * 2 + k];
    const int widx = branch * 4 + e;

    __shared__ __align__(16) float plane[34 * PSTRIDE];
    __shared__ float wsm[8 * 576];

    const float* wsrc = We1 + ((size_t)widx * 64 + ocb) * 576;
    for (int i = t; i < 8 * 576; i += 256) wsm[i] = wsrc[i];

    float acc[8][2][4];
    #pragma unroll
    for (int g = 0; g < 8; ++g) {
        const float bias = be1[widx * 64 + ocb + g];
        #pragma unroll
        for (int rr = 0; rr < 2; ++rr)
            #pragma unroll
            for (int cc = 0; cc < 4; ++cc) acc[g][rr][cc] = bias;
    }

    const float* xin = x + (size_t)b * CH * NPIX;
    const int pr = t >> 4;     // 0..15 -> row pair
    const int pc = t & 15;     // 0..15 -> col quad

    for (int ic = 0; ic < CH; ++ic) {
        __syncthreads();
        const float* src = xin + ic * NPIX;
        for (int idx = t; idx < 34 * 66; idx += 256) {
            const int r = idx / 66, c = idx - r * 66;
            const int gr = z * 32 + r - 1, gc = c - 1;
            float v = 0.f;
            if (gr >= 0 && gr < HW && gc >= 0 && gc < HW) v = src[gr * HW + gc];
            plane[r * PSTRIDE + c] = v;
        }
        __syncthreads();

        float pl[4][6];
        #pragma unroll
        for (int rr = 0; rr < 4; ++rr) {
            const float4 p4 = *(const float4*)&plane[(pr*2 + rr) * PSTRIDE + pc*4];
            const float2 p2 = *(const float2*)&plane[(pr*2 + rr) * PSTRIDE + pc*4 + 4];
            pl[rr][0]=p4.x; pl[rr][1]=p4.y; pl[rr][2]=p4.z; pl[rr][3]=p4.w;
            pl[rr][4]=p2.x; pl[rr][5]=p2.y;
        }
        #pragma unroll
        for (int g = 0; g < 8; ++g) {
            const float* wp = &wsm[g * 576 + ic * 9];
            #pragma unroll
            for (int dy = 0; dy < 3; ++dy)
                #pragma unroll
                for (int dx = 0; dx < 3; ++dx) {
                    const float w = wp[dy * 3 + dx];
                    #pragma unroll
                    for (int rr = 0; rr < 2; ++rr)
                        #pragma unroll
                        for (int cc = 0; cc < 4; ++cc)
                            acc[g][rr][cc] = fmaf(pl[rr+dy][cc+dx], w, acc[g][rr][cc]);
                }
        }
    }

    #pragma unroll
    for (int g = 0; g < 8; ++g) {
        #pragma unroll
        for (int rr = 0; rr < 2; ++rr) {
            const int row = z * 32 + pr * 2 + rr;
            float4 v;
            v.x = lrelu(acc[g][rr][0]); v.y = lrelu(acc[g][rr][1]);
            v.z = lrelu(acc[g][rr][2]); v.w = lrelu(acc[g][rr][3]);
            *(float4*)&h[((size_t)slot * 64 + ocb + g) * NPIX + row * HW + pc * 4] = v;
        }
    }
}

// ---------------------------------------------------------------------------
// conv2 + gated combine: out[b] = sum_k g_k * (conv3x3(h_k, We2[e_k]) + be2[e_k])
// Gate folded into LDS-staged weights; bias folded into acc init.
// grid (b=32, ocg=8, half=2), 256 threads.
// ---------------------------------------------------------------------------
__global__ __launch_bounds__(256) void conv2_kernel(
    const float* __restrict__ h,      // [64][64][4096]
    const int* __restrict__ sel, const float* __restrict__ gv,
    const float* __restrict__ We2,    // [8][64][64][9]
    const float* __restrict__ be2,    // [8][64]
    float* __restrict__ outb,         // [32][64][4096]
    int branch)
{
    const int b   = blockIdx.x;
    const int ocb = blockIdx.y * 8;
    const int z   = blockIdx.z;
    const int t   = threadIdx.x;

    const int base = (branch * 32 + b) * 2;
    const int e0 = sel[base], e1 = sel[base + 1];
    const float g0 = gv[base], g1 = gv[base + 1];

    __shared__ __align__(16) float plane[34 * PSTRIDE];
    __shared__ float wsm[8 * 576];

    float acc[8][2][4];
    #pragma unroll
    for (int g = 0; g < 8; ++g) {
        const float bias = g0 * be2[(branch*4 + e0) * 64 + ocb + g]
                         + g1 * be2[(branch*4 + e1) * 64 + ocb + g];
        #pragma unroll
        for (int rr = 0; rr < 2; ++rr)
            #pragma unroll
            for (int cc = 0; cc < 4; ++cc) acc[g][rr][cc] = bias;
    }

    const int pr = t >> 4, pc = t & 15;

    for (int k = 0; k < 2; ++k) {
        const int   e  = (k == 0) ? e0 : e1;
        const float gk = (k == 0) ? g0 : g1;
        const int widx = branch * 4 + e;
        __syncthreads();   // previous iteration's wsm reads complete
        const float* wsrc = We2 + ((size_t)widx * 64 + ocb) * 576;
        for (int i = t; i < 8 * 576; i += 256) wsm[i] = gk * wsrc[i];

        const float* hin = h + (size_t)(b * 2 + k) * CH * NPIX;
        for (int ic = 0; ic < CH; ++ic) {
            __syncthreads();
            const float* src = hin + ic * NPIX;
            for (int idx = t; idx < 34 * 66; idx += 256) {
                const int r = idx / 66, c = idx - r * 66;
                const int gr = z * 32 + r - 1, gc = c - 1;
                float v = 0.f;
                if (gr >= 0 && gr < HW && gc >= 0 && gc < HW) v = src[gr * HW + gc];
                plane[r * PSTRIDE + c] = v;
            }
            __syncthreads();

            float pl[4][6];
            #pragma unroll
            for (int rr = 0; rr < 4; ++rr) {
                const float4 p4 = *(const float4*)&plane[(pr*2 + rr) * PSTRIDE + pc*4];
                const float2 p2 = *(const float2*)&plane[(pr*2 + rr) * PSTRIDE + pc*4 + 4];
                pl[rr][0]=p4.x; pl[rr][1]=p4.y; pl[rr][2]=p4.z; pl[rr][3]=p4.w;
                pl[rr][4]=p2.x; pl[rr][5]=p2.y;
            }
            #pragma unroll
            for (int g = 0; g < 8; ++g) {
                const float* wp = &wsm[g * 576 + ic * 9];
                #pragma unroll
                for (int dy = 0; dy < 3; ++dy)
                    #pragma unroll
                    for (int dx = 0; dx < 3; ++dx) {
                        const float w = wp[dy * 3 + dx];
                        #pragma unroll
                        for (int rr = 0; rr < 2; ++rr)
                            #pragma unroll
                            for (int cc = 0; cc < 4; ++cc)
                                acc[g][rr][cc] = fmaf(pl[rr+dy][cc+dx], w, acc[g][rr][cc]);
                    }
            }
        }
    }

    #pragma unroll
    for (int g = 0; g < 8; ++g) {
        #pragma unroll
        for (int rr = 0; rr < 2; ++rr) {
            const int row = z * 32 + pr * 2 + rr;
            float4 v;
            v.x = acc[g][rr][0]; v.y = acc[g][rr][1];
            v.z = acc[g][rr][2]; v.w = acc[g][rr][3];
            *(float4*)&outb[((size_t)b * 64 + ocb + g) * NPIX + row * HW + pc * 4] = v;
        }
    }
}

// ---------------------------------------------------------------------------
// reduce conv: out = conv3x3(concat([out_rgb, out_ir], ch), Wr) + br
// grid (b=32, ocg=8, half=2), 256 threads. 128 input channels.
// ---------------------------------------------------------------------------
__global__ __launch_bounds__(256) void reduce_kernel(
    const float* __restrict__ out_rgb,  // [32][64][4096]
    const float* __restrict__ out_ir,   // [32][64][4096]
    const float* __restrict__ Wr,       // [64][128][9]
    const float* __restrict__ brb,      // [64]
    float* __restrict__ out)            // [32][64][4096]
{
    const int b   = blockIdx.x;
    const int ocb = blockIdx.y * 8;
    const int z   = blockIdx.z;
    const int t   = threadIdx.x;

    __shared__ __align__(16) float plane[34 * PSTRIDE];
    __shared__ float wsm[8 * 1152];

    const float* wsrc = Wr + (size_t)ocb * 1152;
    for (int i = t; i < 8 * 1152; i += 256) wsm[i] = wsrc[i];

    float acc[8][2][4];
    #pragma unroll
    for (int g = 0; g < 8; ++g) {
        const float bias = brb[ocb + g];
        #pragma unroll
        for (int rr = 0; rr < 2; ++rr)
            #pragma unroll
            for (int cc = 0; cc < 4; ++cc) acc[g][rr][cc] = bias;
    }

    const int pr = t >> 4, pc = t & 15;

    for (int ic = 0; ic < 128; ++ic) {
        __syncthreads();
        const float* src = (ic < 64)
            ? out_rgb + ((size_t)b * 64 + ic) * NPIX
            : out_ir  + ((size_t)b * 64 + (ic - 64)) * NPIX;
        for (int idx = t; idx < 34 * 66; idx += 256) {
            const int r = idx / 66, c = idx - r * 66;
            const int gr = z * 32 + r - 1, gc = c - 1;
            float v = 0.f;
            if (gr >= 0 && gr < HW && gc >= 0 && gc < HW) v = src[gr * HW + gc];
            plane[r * PSTRIDE + c] = v;
        }
        __syncthreads();

        float pl[4][6];
        #pragma unroll
        for (int rr = 0; rr < 4; ++rr) {
            const float4 p4 = *(const float4*)&plane[(pr*2 + rr) * PSTRIDE + pc*4];
            const float2 p2 = *(const float2*)&plane[(pr*2 + rr) * PSTRIDE + pc*4 + 4];
            pl[rr][0]=p4.x; pl[rr][1]=p4.y; pl[rr][2]=p4.z; pl[rr][3]=p4.w;
            pl[rr][4]=p2.x; pl[rr][5]=p2.y;
        }
        #pragma unroll
        for (int g = 0; g < 8; ++g) {
            const float* wp = &wsm[g * 1152 + ic * 9];
            #pragma unroll
            for (int dy = 0; dy < 3; ++dy)
                #pragma unroll
                for (int dx = 0; dx < 3; ++dx) {
                    const float w = wp[dy * 3 + dx];
                    #pragma unroll
                    for (int rr = 0; rr < 2; ++rr)
                        #pragma unroll
                        for (int cc = 0; cc < 4; ++cc)
                            acc[g][rr][cc] = fmaf(pl[rr+dy][cc+dx], w, acc[g][rr][cc]);
                }
        }
    }

    #pragma unroll
    for (int g = 0; g < 8; ++g) {
        #pragma unroll
        for (int rr = 0; rr < 2; ++rr) {
            const int row = z * 32 + pr * 2 + rr;
            float4 v;
            v.x = acc[g][rr][0]; v.y = acc[g][rr][1];
            v.z = acc[g][rr][2]; v.w = acc[g][rr][3];
            *(float4*)&out[((size_t)b * 64 + ocb + g) * NPIX + row * HW + pc * 4] = v;
        }
    }
}

// ---------------------------------------------------------------------------
extern "C" void kernel_launch(void* const* d_in, const int* in_sizes, int n_in,
                              void* d_out, int out_size, void* d_ws, size_t ws_size,
                              hipStream_t stream)
{
    const float* x_rgb  = (const float*)d_in[0];
    const float* x_ir   = (const float*)d_in[1];
    const float* n_rgb  = (const float*)d_in[2];
    const float* n_ir   = (const float*)d_in[3];
    const float* wg_rgb = (const float*)d_in[4];
    const float* wn_rgb = (const float*)d_in[5];
    const float* wg_ir  = (const float*)d_in[6];
    const float* wn_ir  = (const float*)d_in[7];
    const float* We1    = (const float*)d_in[8];
    const float* be1    = (const float*)d_in[9];
    const float* We2    = (const float*)d_in[10];
    const float* be2    = (const float*)d_in[11];
    const float* Wr     = (const float*)d_in[12];
    const float* brb    = (const float*)d_in[13];
    float* out = (float*)d_out;

    // workspace layout (floats):
    //   [0,128)           sel (as int)
    //   [128,256)         gate values
    //   [256, +64MB)      h buffer: 64 slots x 64ch x 4096 (reused per branch)
    //   then out_rgb (32MB), out_ir (32MB)
    int*   sel = (int*)d_ws;
    float* gv  = (float*)d_ws + 128;
    float* h   = (float*)d_ws + 256;
    float* orgb = h + (size_t)64 * 64 * NPIX;
    float* oir  = orgb + (size_t)32 * 64 * NPIX;

    gating_kernel<<<64, 256, 0, stream>>>(x_rgb, x_ir, n_rgb, n_ir,
                                          wg_rgb, wn_rgb, wg_ir, wn_ir, sel, gv);

    conv1_kernel<<<dim3(64, 8, 2), 256, 0, stream>>>(x_rgb, sel, We1, be1, h, 0);
    conv2_kernel<<<dim3(32, 8, 2), 256, 0, stream>>>(h, sel, gv, We2, be2, orgb, 0);

    conv1_kernel<<<dim3(64, 8, 2), 256, 0, stream>>>(x_ir, sel, We1, be1, h, 1);
    conv2_kernel<<<dim3(32, 8, 2), 256, 0, stream>>>(h, sel, gv, We2, be2, oir, 1);

    reduce_kernel<<<dim3(32, 8, 2), 256, 0, stream>>>(orgb, oir, Wr, brb, out);
}

// Round 5
// 689.416 us; speedup vs baseline: 4.0246x; 4.0246x over previous
//
#include <hip/hip_runtime.h>
#include <hip/hip_bf16.h>
#include <cstdint>
#include <cmath>

#define BATCH 32
#define CH 64
#define HW 64
#define NPIX 4096
#define DFLAT 262144

typedef short bf16x8 __attribute__((ext_vector_type(8)));
typedef float f32x16 __attribute__((ext_vector_type(16)));
typedef unsigned short u16;
typedef unsigned int u32;
typedef unsigned long long u64;

static __device__ __forceinline__ float lrelu(float v) {
    return v > 0.f ? v : 0.2f * v;
}
// f32 -> bf16 RNE, bit-level (no header API dependence)
static __device__ __forceinline__ u16 f2bf(float f) {
    u32 u = __float_as_uint(f);
    u = (u + 0x7FFFu + ((u >> 16) & 1u)) >> 16;
    return (u16)u;
}

static __device__ __forceinline__ f32x16 mfma32(bf16x8 a, bf16x8 b, f32x16 c) {
    return __builtin_amdgcn_mfma_f32_32x32x16_bf16(a, b, c, 0, 0, 0);
}

// ---------------------------------------------------------------------------
// Gating (f32, unchanged — selection must match reference).
// ---------------------------------------------------------------------------
__global__ __launch_bounds__(256) void gating_kernel(
    const float* __restrict__ x_rgb, const float* __restrict__ x_ir,
    const float* __restrict__ n_rgb, const float* __restrict__ n_ir,
    const float* __restrict__ wg_rgb, const float* __restrict__ wn_rgb,
    const float* __restrict__ wg_ir,  const float* __restrict__ wn_ir,
    int* __restrict__ sel, float* __restrict__ gv)
{
    const int br = blockIdx.x >> 5;
    const int b  = blockIdx.x & 31;
    const float*  x  = (br ? x_ir : x_rgb) + (size_t)b * DFLAT;
    const float4* wg = (const float4*)(br ? wg_ir : wg_rgb);
    const float4* wn = (const float4*)(br ? wn_ir : wn_rgb);
    const float*  nz = (br ? n_ir : n_rgb) + b * 4;
    const int t = threadIdx.x;

    float cg0=0.f,cg1=0.f,cg2=0.f,cg3=0.f;
    float cn0=0.f,cn1=0.f,cn2=0.f,cn3=0.f;
    for (int i = 0; i < DFLAT/256; ++i) {
        const int d = (i << 8) + t;
        const float  xv = x[d];
        const float4 g4 = wg[d];
        const float4 n4 = wn[d];
        cg0 = fmaf(xv, g4.x, cg0); cg1 = fmaf(xv, g4.y, cg1);
        cg2 = fmaf(xv, g4.z, cg2); cg3 = fmaf(xv, g4.w, cg3);
        cn0 = fmaf(xv, n4.x, cn0); cn1 = fmaf(xv, n4.y, cn1);
        cn2 = fmaf(xv, n4.z, cn2); cn3 = fmaf(xv, n4.w, cn3);
    }

    __shared__ float red[8][256];
    red[0][t]=cg0; red[1][t]=cg1; red[2][t]=cg2; red[3][t]=cg3;
    red[4][t]=cn0; red[5][t]=cn1; red[6][t]=cn2; red[7][t]=cn3;
    __syncthreads();
    for (int s = 128; s > 0; s >>= 1) {
        if (t < s) {
            #pragma unroll
            for (int v = 0; v < 8; ++v) red[v][t] += red[v][t + s];
        }
        __syncthreads();
    }

    if (t == 0) {
        float logit[4];
        #pragma unroll
        for (int e = 0; e < 4; ++e) {
            const float clean = red[e][0];
            const float zz    = red[4 + e][0];
            const float sp    = fmaxf(zz, 0.f) + log1pf(expf(-fabsf(zz)));
            logit[e] = clean + nz[e] * (sp + 1e-2f);
        }
        int i1 = 0;
        #pragma unroll
        for (int e = 1; e < 4; ++e) if (logit[e] > logit[i1]) i1 = e;
        int i2 = (i1 == 0) ? 1 : 0;
        #pragma unroll
        for (int e = 0; e < 4; ++e)
            if (e != i1 && logit[e] > logit[i2]) i2 = e;
        const float ex = expf(logit[i2] - logit[i1]);
        const float s  = 1.f + ex;
        const int base = (br * 32 + b) * 2;
        sel[base]     = i1;
        sel[base + 1] = i2;
        gv[base]      = 1.f / s;
        gv[base + 1]  = ex / s;
    }
}

// ---------------------------------------------------------------------------
// Weight packing: A-pack layout [widx][kstep s][oc][16 k] bf16.
//   s = (ky*3+kx)*4 + q ; k-global = tap*ICS + q*16 + kl
// A1/A2: [8][36][64][16]  (K=576: 9 taps x 64 ic)
// Ar:    [2][36][64][16]  (K=1152: half = channel group, 9 taps x 64 ic each)
// ---------------------------------------------------------------------------
__global__ __launch_bounds__(256) void prep_kernel(
    const float* __restrict__ We1, const float* __restrict__ We2,
    const float* __restrict__ Wr,
    u16* __restrict__ A1, u16* __restrict__ A2, u16* __restrict__ Ar)
{
    const int id = blockIdx.x * 256 + threadIdx.x;
    const int T1 = 8 * 36 * 64 * 16;      // 294912
    if (id < 2 * T1) {
        const float* W = (id < T1) ? We1 : We2;
        u16* A = (id < T1) ? A1 : A2;
        const int i  = (id < T1) ? id : id - T1;
        const int kl = i & 15;
        const int oc = (i >> 4) & 63;
        const int sw = i >> 10;            // widx*36 + s
        const int s  = sw % 36, widx = sw / 36;
        const int tap = s >> 2, q = s & 3;
        const int ky = tap / 3, kx = tap % 3;
        const int ic = q * 16 + kl;
        A[i] = f2bf(W[(((size_t)(widx * 64 + oc) * 64 + ic) * 3 + ky) * 3 + kx]);
    } else {
        const int i = id - 2 * T1;
        if (i >= 2 * 36 * 64 * 16) return;
        const int kl = i & 15;
        const int oc = (i >> 4) & 63;
        const int sh = i >> 10;            // half*36 + s
        const int s  = sh % 36, half = sh / 36;
        const int tap = s >> 2, q = s & 3;
        const int ky = tap / 3, kx = tap % 3;
        const int icg = half * 64 + q * 16 + kl;
        Ar[i] = f2bf(Wr[(((size_t)oc * 128 + icg) * 3 + ky) * 3 + kx]);
    }
}

// ---------------------------------------------------------------------------
// Implicit-GEMM conv3x3 via mfma_f32_32x32x16_bf16.
// Block: 256 thr = 4 waves. Tile: 4 rows x 64 cols; wave w -> row r0+w,
// 64 oc x 64 pix = 2(M) x 2(N) fragments.
// LDS: input staged transposed [pix = 6 rows x 66 cols][64 ic] bf16,
// 8B-slot swizzle slot = (ic>>2) ^ (pix&15) -> conflict-free ds_read_b64.
// A fragments read from global packed weights (L2-resident).
// MODE 0: conv1 (f32 in, lrelu, bf16 out to h)
// MODE 1: conv2 (bf16 h in, 2 experts gated into one acc, bf16 out)
// MODE 2: reduce (bf16 branch outputs, 128 ic, f32 out)
// ---------------------------------------------------------------------------
template<int MODE>
__global__ __launch_bounds__(256) void conv_mfma(
    const void* __restrict__ inA, const void* __restrict__ inB,
    const u16* __restrict__ Apack,
    const float* __restrict__ biasT,
    const int* __restrict__ sel, const float* __restrict__ gvv,
    void* __restrict__ outp)
{
    const int t = threadIdx.x;
    const int l = t & 63;
    const int w = t >> 6;
    const int r0 = blockIdx.y * 4;

    __shared__ __align__(16) u32 smem[396 * 32];   // 50688 B

    const int NH = (MODE == 0) ? 1 : 2;

    const void* src[2];
    const u16*  ab[2];
    const float* bptr0 = nullptr; const float* bptr1 = nullptr;
    float g0 = 0.f, g1 = 0.f;
    void* outbase;

    if (MODE == 0) {
        const int s = blockIdx.x;            // branch*64 + b*2 + k
        const int branch = s >> 6, slot6 = s & 63;
        const int b = slot6 >> 1, k = slot6 & 1;
        const int e = sel[(branch * 32 + b) * 2 + k];
        const int widx = branch * 4 + e;
        src[0] = (const void*)((const float*)(branch ? inB : inA) + (size_t)b * DFLAT);
        src[1] = src[0];
        ab[0] = Apack + (size_t)widx * 36864; ab[1] = ab[0];
        bptr0 = biasT + widx * 64;
        outbase = (void*)((u16*)outp + (size_t)s * DFLAT);
    } else if (MODE == 1) {
        const int s = blockIdx.x;            // branch*32 + b
        const int branch = s >> 5, b = s & 31;
        const int base2 = (branch * 32 + b) * 2;
        const int e0 = sel[base2], e1 = sel[base2 + 1];
        g0 = gvv[base2]; g1 = gvv[base2 + 1];
        src[0] = (const void*)((const u16*)inA + (size_t)(branch * 64 + b * 2 + 0) * DFLAT);
        src[1] = (const void*)((const u16*)inA + (size_t)(branch * 64 + b * 2 + 1) * DFLAT);
        ab[0] = Apack + (size_t)(branch * 4 + e0) * 36864;
        ab[1] = Apack + (size_t)(branch * 4 + e1) * 36864;
        bptr0 = biasT + (branch * 4 + e0) * 64;
        bptr1 = biasT + (branch * 4 + e1) * 64;
        outbase = (void*)((u16*)outp + (size_t)s * DFLAT);
    } else {
        const int b = blockIdx.x;
        src[0] = (const void*)((const u16*)inA + (size_t)(0 * 32 + b) * DFLAT);
        src[1] = (const void*)((const u16*)inA + (size_t)(1 * 32 + b) * DFLAT);
        ab[0] = Apack;
        ab[1] = Apack + 36864;
        bptr0 = biasT;
        outbase = (void*)((float*)outp + (size_t)b * DFLAT);
    }

    f32x16 acc[2][2];
    #pragma unroll
    for (int m = 0; m < 2; ++m)
        #pragma unroll
        for (int n = 0; n < 2; ++n)
            #pragma unroll
            for (int r = 0; r < 16; ++r) acc[m][n][r] = 0.f;

    for (int half = 0; half < NH; ++half) {
        if (half) __syncthreads();           // finish prior half's LDS reads
        // ---- stage tile transposed into LDS (zero-filled halo) ----
        for (int idx = t; idx < 12672; idx += 256) {
            const int icp = idx / 396;       // 0..31 (ic pair)
            const int pix = idx - icp * 396; // 0..395, lanes ~consecutive pixels
            const int row = pix / 66;
            const int col = pix - row * 66;
            const int ir  = r0 - 1 + row;
            const int jc  = col - 1;
            const int ich = icp * 2;
            u32 val = 0;
            if ((unsigned)ir < 64u && (unsigned)jc < 64u) {
                const int off = ir * 64 + jc;
                if (MODE == 0) {
                    const float* fp = (const float*)src[half];
                    val = (u32)f2bf(fp[ich * NPIX + off])
                        | ((u32)f2bf(fp[(ich + 1) * NPIX + off]) << 16);
                } else {
                    const u16* up = (const u16*)src[half];
                    val = (u32)up[ich * NPIX + off]
                        | ((u32)up[(ich + 1) * NPIX + off] << 16);
                }
            }
            smem[pix * 32 + (((ich >> 2) ^ (pix & 15)) << 1) + ((ich & 2) >> 1)] = val;
        }
        __syncthreads();

        // ---- K loop: 9 taps x 4 ksteps of 16 ic ----
        const u16* Ab = ab[half];
        for (int tap = 0; tap < 9; ++tap) {
            const int ky = tap / 3, kx = tap % 3;
            const int pbase = (w + ky) * 66 + kx;
            #pragma unroll
            for (int q = 0; q < 4; ++q) {
                const int s = tap * 4 + q;
                bf16x8 af[2], bfr[2];
                #pragma unroll
                for (int m = 0; m < 2; ++m)
                    af[m] = *(const bf16x8*)(Ab + ((size_t)(s * 64 + 32 * m + (l & 31)) << 4)
                                                + ((l >> 5) << 3));
                #pragma unroll
                for (int n = 0; n < 2; ++n) {
                    const int pix  = pbase + 32 * n + (l & 31);
                    const int ic0  = q * 16 + ((l >> 5) << 3);
                    const int slot = (ic0 >> 2) ^ (pix & 15);
                    union { u64 u[2]; bf16x8 v; } bu;
                    bu.u[0] = *(const u64*)&smem[pix * 32 + slot * 2];
                    bu.u[1] = *(const u64*)&smem[pix * 32 + (slot ^ 1) * 2];
                    bfr[n] = bu.v;
                }
                acc[0][0] = mfma32(af[0], bfr[0], acc[0][0]);
                acc[0][1] = mfma32(af[0], bfr[1], acc[0][1]);
                acc[1][0] = mfma32(af[1], bfr[0], acc[1][0]);
                acc[1][1] = mfma32(af[1], bfr[1], acc[1][1]);
            }
        }
        if (MODE == 1 && half == 0) {
            const float ratio = g0 / g1;     // g1>0 (softmax of top-2)
            #pragma unroll
            for (int m = 0; m < 2; ++m)
                #pragma unroll
                for (int n = 0; n < 2; ++n)
                    #pragma unroll
                    for (int r = 0; r < 16; ++r) acc[m][n][r] *= ratio;
        }
    }

    // ---- epilogue: C/D row = (r&3)+8*(r>>2)+4*(l>>5), col = l&31 ----
    #pragma unroll
    for (int m = 0; m < 2; ++m) {
        #pragma unroll
        for (int n = 0; n < 2; ++n) {
            #pragma unroll
            for (int r = 0; r < 16; ++r) {
                const int oc   = 32 * m + (r & 3) + ((r >> 2) << 3) + ((l >> 5) << 2);
                const int colp = 32 * n + (l & 31);
                const size_t off = (size_t)oc * NPIX + (size_t)(r0 + w) * 64 + colp;
                float v = acc[m][n][r];
                if (MODE == 0) {
                    v = lrelu(v + bptr0[oc]);
                    ((u16*)outbase)[off] = f2bf(v);
                } else if (MODE == 1) {
                    v = v * g1 + g0 * bptr0[oc] + g1 * bptr1[oc];
                    ((u16*)outbase)[off] = f2bf(v);
                } else {
                    ((float*)outbase)[off] = v + bptr0[oc];
                }
            }
        }
    }
}

// ---------------------------------------------------------------------------
extern "C" void kernel_launch(void* const* d_in, const int* in_sizes, int n_in,
                              void* d_out, int out_size, void* d_ws, size_t ws_size,
                              hipStream_t stream)
{
    const float* x_rgb  = (const float*)d_in[0];
    const float* x_ir   = (const float*)d_in[1];
    const float* n_rgb  = (const float*)d_in[2];
    const float* n_ir   = (const float*)d_in[3];
    const float* wg_rgb = (const float*)d_in[4];
    const float* wn_rgb = (const float*)d_in[5];
    const float* wg_ir  = (const float*)d_in[6];
    const float* wn_ir  = (const float*)d_in[7];
    const float* We1    = (const float*)d_in[8];
    const float* be1    = (const float*)d_in[9];
    const float* We2    = (const float*)d_in[10];
    const float* be2    = (const float*)d_in[11];
    const float* Wr     = (const float*)d_in[12];
    const float* brb    = (const float*)d_in[13];
    float* out = (float*)d_out;

    // workspace layout (bytes) — NOTE: sizes are BYTES = 2 * element count.
    //   sel    @ 0         512 B
    //   gv     @ 512       512 B
    //   A1     @ 1024      294912 u16 = 589824 B
    //   A2     @ 590848    294912 u16 = 589824 B
    //   Ar     @ 1180672    73728 u16 = 147456 B
    //   h      @ 1328128   128*262144 u16 = 67108864 B
    //   obr    @ 68436992   64*262144 u16 = 33554432 B
    char* ws = (char*)d_ws;
    int*   sel = (int*)(ws + 0);
    float* gv  = (float*)(ws + 512);
    u16* A1  = (u16*)(ws + 1024);
    u16* A2  = (u16*)(ws + 590848);
    u16* Ar  = (u16*)(ws + 1180672);
    u16* h   = (u16*)(ws + 1328128);
    u16* obr = (u16*)(ws + 68436992);

    prep_kernel<<<2592, 256, 0, stream>>>(We1, We2, Wr, A1, A2, Ar);
    gating_kernel<<<64, 256, 0, stream>>>(x_rgb, x_ir, n_rgb, n_ir,
                                          wg_rgb, wn_rgb, wg_ir, wn_ir, sel, gv);

    conv_mfma<0><<<dim3(128, 16), 256, 0, stream>>>(x_rgb, x_ir, A1, be1, sel, gv, h);
    conv_mfma<1><<<dim3(64, 16),  256, 0, stream>>>(h, nullptr, A2, be2, sel, gv, obr);
    conv_mfma<2><<<dim3(32, 16),  256, 0, stream>>>(obr, nullptr, Ar, brb, sel, gv, out);
}

// Round 7
// 485.288 us; speedup vs baseline: 5.7175x; 1.4206x over previous
//
#include <hip/hip_runtime.h>
#include <hip/hip_bf16.h>
#include <cstdint>
#include <cmath>

#define BATCH 32
#define CH 64
#define HW 64
#define NPIX 4096
#define DFLAT 262144

typedef short bf16x8 __attribute__((ext_vector_type(8)));
typedef float f32x16 __attribute__((ext_vector_type(16)));
typedef unsigned short u16;
typedef unsigned int u32;
typedef unsigned long long u64;

static __device__ __forceinline__ float lrelu(float v) {
    return v > 0.f ? v : 0.2f * v;
}
// f32 -> bf16 RNE, bit-level (no header API dependence)
static __device__ __forceinline__ u16 f2bf(float f) {
    u32 u = __float_as_uint(f);
    u = (u + 0x7FFFu + ((u >> 16) & 1u)) >> 16;
    return (u16)u;
}

static __device__ __forceinline__ f32x16 mfma32(bf16x8 a, bf16x8 b, f32x16 c) {
    return __builtin_amdgcn_mfma_f32_32x32x16_bf16(a, b, c, 0, 0, 0);
}

// ---------------------------------------------------------------------------
// Gating phase 1: split-K partial dot products.
// grid (64 = branch*32+b, 32 = k-chunk), 256 thr. Each block reduces an
// 8192-element chunk into 8 partials (4 gate + 4 noise cols).
// Round-5 profile: monolithic gating was 267us at 2.9% occupancy (64 blocks).
// ---------------------------------------------------------------------------
__global__ __launch_bounds__(256) void gating_partial(
    const float* __restrict__ x_rgb, const float* __restrict__ x_ir,
    const float* __restrict__ wg_rgb, const float* __restrict__ wn_rgb,
    const float* __restrict__ wg_ir,  const float* __restrict__ wn_ir,
    float* __restrict__ partial)      // [64][32][8]
{
    const int sb = blockIdx.x;         // branch*32 + b
    const int ck = blockIdx.y;         // 0..31
    const int br = sb >> 5, b = sb & 31;
    const float*  x  = (br ? x_ir : x_rgb) + (size_t)b * DFLAT + ck * 8192;
    const float4* wg = (const float4*)(br ? wg_ir : wg_rgb) + ck * 8192;
    const float4* wn = (const float4*)(br ? wn_ir : wn_rgb) + ck * 8192;
    const int t = threadIdx.x;

    float cg0=0.f,cg1=0.f,cg2=0.f,cg3=0.f;
    float cn0=0.f,cn1=0.f,cn2=0.f,cn3=0.f;
    for (int i = 0; i < 32; ++i) {
        const int d = (i << 8) + t;
        const float  xv = x[d];
        const float4 g4 = wg[d];
        const float4 n4 = wn[d];
        cg0 = fmaf(xv, g4.x, cg0); cg1 = fmaf(xv, g4.y, cg1);
        cg2 = fmaf(xv, g4.z, cg2); cg3 = fmaf(xv, g4.w, cg3);
        cn0 = fmaf(xv, n4.x, cn0); cn1 = fmaf(xv, n4.y, cn1);
        cn2 = fmaf(xv, n4.z, cn2); cn3 = fmaf(xv, n4.w, cn3);
    }

    __shared__ float red[8][256];
    red[0][t]=cg0; red[1][t]=cg1; red[2][t]=cg2; red[3][t]=cg3;
    red[4][t]=cn0; red[5][t]=cn1; red[6][t]=cn2; red[7][t]=cn3;
    __syncthreads();
    for (int s = 128; s > 0; s >>= 1) {
        if (t < s) {
            #pragma unroll
            for (int v = 0; v < 8; ++v) red[v][t] += red[v][t + s];
        }
        __syncthreads();
    }
    if (t < 8) partial[((size_t)sb * 32 + ck) * 8 + t] = red[t][0];
}

// ---------------------------------------------------------------------------
// Gating phase 2: sum 32 chunk-partials, then softplus/noisy-top2/softmax
// (identical math to the round-5-verified monolithic kernel).
// ---------------------------------------------------------------------------
__global__ __launch_bounds__(256) void gating_final(
    const float* __restrict__ partial,
    const float* __restrict__ n_rgb, const float* __restrict__ n_ir,
    int* __restrict__ sel, float* __restrict__ gv)
{
    const int sb = blockIdx.x;         // branch*32 + b
    const int br = sb >> 5, b = sb & 31;
    const float* nz = (br ? n_ir : n_rgb) + b * 4;
    const int t = threadIdx.x;

    __shared__ float red[8][32];
    {
        const int v = t >> 5, c = t & 31;
        red[v][c] = partial[((size_t)sb * 32 + c) * 8 + v];
    }
    __syncthreads();
    __shared__ float sums[8];
    if (t < 8) {
        float s = 0.f;
        #pragma unroll
        for (int c = 0; c < 32; ++c) s += red[t][c];
        sums[t] = s;
    }
    __syncthreads();

    if (t == 0) {
        float logit[4];
        #pragma unroll
        for (int e = 0; e < 4; ++e) {
            const float clean = sums[e];
            const float zz    = sums[4 + e];
            const float sp    = fmaxf(zz, 0.f) + log1pf(expf(-fabsf(zz)));
            logit[e] = clean + nz[e] * (sp + 1e-2f);
        }
        int i1 = 0;
        #pragma unroll
        for (int e = 1; e < 4; ++e) if (logit[e] > logit[i1]) i1 = e;
        int i2 = (i1 == 0) ? 1 : 0;
        #pragma unroll
        for (int e = 0; e < 4; ++e)
            if (e != i1 && logit[e] > logit[i2]) i2 = e;
        const float ex = expf(logit[i2] - logit[i1]);
        const float s  = 1.f + ex;
        const int base = sb * 2;
        sel[base]     = i1;
        sel[base + 1] = i2;
        gv[base]      = 1.f / s;
        gv[base + 1]  = ex / s;
    }
}

// ---------------------------------------------------------------------------
// Weight packing: A-pack layout [widx][kstep s][oc][16 k] bf16.
//   s = (ky*3+kx)*4 + q ; k-global = tap*ICS + q*16 + kl
// A1/A2: [8][36][64][16]  (K=576: 9 taps x 64 ic)
// Ar:    [2][36][64][16]  (K=1152: half = channel group, 9 taps x 64 ic each)
// ---------------------------------------------------------------------------
__global__ __launch_bounds__(256) void prep_kernel(
    const float* __restrict__ We1, const float* __restrict__ We2,
    const float* __restrict__ Wr,
    u16* __restrict__ A1, u16* __restrict__ A2, u16* __restrict__ Ar)
{
    const int id = blockIdx.x * 256 + threadIdx.x;
    const int T1 = 8 * 36 * 64 * 16;      // 294912
    if (id < 2 * T1) {
        const float* W = (id < T1) ? We1 : We2;
        u16* A = (id < T1) ? A1 : A2;
        const int i  = (id < T1) ? id : id - T1;
        const int kl = i & 15;
        const int oc = (i >> 4) & 63;
        const int sw = i >> 10;            // widx*36 + s
        const int s  = sw % 36, widx = sw / 36;
        const int tap = s >> 2, q = s & 3;
        const int ky = tap / 3, kx = tap % 3;
        const int ic = q * 16 + kl;
        A[i] = f2bf(W[(((size_t)(widx * 64 + oc) * 64 + ic) * 3 + ky) * 3 + kx]);
    } else {
        const int i = id - 2 * T1;
        if (i >= 2 * 36 * 64 * 16) return;
        const int kl = i & 15;
        const int oc = (i >> 4) & 63;
        const int sh = i >> 10;            // half*36 + s
        const int s  = sh % 36, half = sh / 36;
        const int tap = s >> 2, q = s & 3;
        const int ky = tap / 3, kx = tap % 3;
        const int icg = half * 64 + q * 16 + kl;
        Ar[i] = f2bf(Wr[(((size_t)oc * 128 + icg) * 3 + ky) * 3 + kx]);
    }
}

// ---------------------------------------------------------------------------
// Implicit-GEMM conv3x3 via mfma_f32_32x32x16_bf16.
// Block: 256 thr = 4 waves. Tile: 4 rows x 64 cols; wave w -> row r0+w,
// 64 oc x 64 pix = 2(M) x 2(N) fragments.
// LDS: input staged transposed [pix = 6 rows x 66 cols][64 ic] bf16,
// 8B-slot swizzle slot = (ic>>2) ^ (pix&15) -> conflict-free ds_read_b64.
// A fragments read from global packed weights (L2-resident).
// MODE 0: conv1 (f32 in, lrelu, bf16 out to h)
// MODE 1: conv2 (bf16 h in, 2 experts gated into one acc, bf16 out)
// MODE 2: reduce (bf16 branch outputs, 128 ic, f32 out)
// ---------------------------------------------------------------------------
template<int MODE>
__global__ __launch_bounds__(256) void conv_mfma(
    const void* __restrict__ inA, const void* __restrict__ inB,
    const u16* __restrict__ Apack,
    const float* __restrict__ biasT,
    const int* __restrict__ sel, const float* __restrict__ gvv,
    void* __restrict__ outp)
{
    const int t = threadIdx.x;
    const int l = t & 63;
    const int w = t >> 6;
    const int r0 = blockIdx.y * 4;

    __shared__ __align__(16) u32 smem[396 * 32];   // 50688 B

    const int NH = (MODE == 0) ? 1 : 2;

    const void* src[2];
    const u16*  ab[2];
    const float* bptr0 = nullptr; const float* bptr1 = nullptr;
    float g0 = 0.f, g1 = 0.f;
    void* outbase;

    if (MODE == 0) {
        const int s = blockIdx.x;            // branch*64 + b*2 + k
        const int branch = s >> 6, slot6 = s & 63;
        const int b = slot6 >> 1, k = slot6 & 1;
        const int e = sel[(branch * 32 + b) * 2 + k];
        const int widx = branch * 4 + e;
        src[0] = (const void*)((const float*)(branch ? inB : inA) + (size_t)b * DFLAT);
        src[1] = src[0];
        ab[0] = Apack + (size_t)widx * 36864; ab[1] = ab[0];
        bptr0 = biasT + widx * 64;
        outbase = (void*)((u16*)outp + (size_t)s * DFLAT);
    } else if (MODE == 1) {
        const int s = blockIdx.x;            // branch*32 + b
        const int branch = s >> 5, b = s & 31;
        const int base2 = (branch * 32 + b) * 2;
        const int e0 = sel[base2], e1 = sel[base2 + 1];
        g0 = gvv[base2]; g1 = gvv[base2 + 1];
        src[0] = (const void*)((const u16*)inA + (size_t)(branch * 64 + b * 2 + 0) * DFLAT);
        src[1] = (const void*)((const u16*)inA + (size_t)(branch * 64 + b * 2 + 1) * DFLAT);
        ab[0] = Apack + (size_t)(branch * 4 + e0) * 36864;
        ab[1] = Apack + (size_t)(branch * 4 + e1) * 36864;
        bptr0 = biasT + (branch * 4 + e0) * 64;
        bptr1 = biasT + (branch * 4 + e1) * 64;
        outbase = (void*)((u16*)outp + (size_t)s * DFLAT);
    } else {
        const int b = blockIdx.x;
        src[0] = (const void*)((const u16*)inA + (size_t)(0 * 32 + b) * DFLAT);
        src[1] = (const void*)((const u16*)inA + (size_t)(1 * 32 + b) * DFLAT);
        ab[0] = Apack;
        ab[1] = Apack + 36864;
        bptr0 = biasT;
        outbase = (void*)((float*)outp + (size_t)b * DFLAT);
    }

    f32x16 acc[2][2];
    #pragma unroll
    for (int m = 0; m < 2; ++m)
        #pragma unroll
        for (int n = 0; n < 2; ++n)
            #pragma unroll
            for (int r = 0; r < 16; ++r) acc[m][n][r] = 0.f;

    for (int half = 0; half < NH; ++half) {
        if (half) __syncthreads();           // finish prior half's LDS reads
        // ---- stage tile transposed into LDS (zero-filled halo) ----
        for (int idx = t; idx < 12672; idx += 256) {
            const int icp = idx / 396;       // 0..31 (ic pair)
            const int pix = idx - icp * 396; // 0..395
            const int row = pix / 66;
            const int col = pix - row * 66;
            const int ir  = r0 - 1 + row;
            const int jc  = col - 1;
            const int ich = icp * 2;
            u32 val = 0;
            if ((unsigned)ir < 64u && (unsigned)jc < 64u) {
                const int off = ir * 64 + jc;
                if (MODE == 0) {
                    const float* fp = (const float*)src[half];
                    val = (u32)f2bf(fp[ich * NPIX + off])
                        | ((u32)f2bf(fp[(ich + 1) * NPIX + off]) << 16);
                } else {
                    const u16* up = (const u16*)src[half];
                    val = (u32)up[ich * NPIX + off]
                        | ((u32)up[(ich + 1) * NPIX + off] << 16);
                }
            }
            smem[pix * 32 + (((ich >> 2) ^ (pix & 15)) << 1) + ((ich & 2) >> 1)] = val;
        }
        __syncthreads();

        // ---- K loop: 9 taps x 4 ksteps of 16 ic ----
        const u16* Ab = ab[half];
        for (int tap = 0; tap < 9; ++tap) {
            const int ky = tap / 3, kx = tap % 3;
            const int pbase = (w + ky) * 66 + kx;
            #pragma unroll
            for (int q = 0; q < 4; ++q) {
                const int s = tap * 4 + q;
                bf16x8 af[2], bfr[2];
                #pragma unroll
                for (int m = 0; m < 2; ++m)
                    af[m] = *(const bf16x8*)(Ab + ((size_t)(s * 64 + 32 * m + (l & 31)) << 4)
                                                + ((l >> 5) << 3));
                #pragma unroll
                for (int n = 0; n < 2; ++n) {
                    const int pix  = pbase + 32 * n + (l & 31);
                    const int ic0  = q * 16 + ((l >> 5) << 3);
                    const int slot = (ic0 >> 2) ^ (pix & 15);
                    union { u64 u[2]; bf16x8 v; } bu;
                    bu.u[0] = *(const u64*)&smem[pix * 32 + slot * 2];
                    bu.u[1] = *(const u64*)&smem[pix * 32 + (slot ^ 1) * 2];
                    bfr[n] = bu.v;
                }
                acc[0][0] = mfma32(af[0], bfr[0], acc[0][0]);
                acc[0][1] = mfma32(af[0], bfr[1], acc[0][1]);
                acc[1][0] = mfma32(af[1], bfr[0], acc[1][0]);
                acc[1][1] = mfma32(af[1], bfr[1], acc[1][1]);
            }
        }
        if (MODE == 1 && half == 0) {
            const float ratio = g0 / g1;     // g1>0 (softmax of top-2)
            #pragma unroll
            for (int m = 0; m < 2; ++m)
                #pragma unroll
                for (int n = 0; n < 2; ++n)
                    #pragma unroll
                    for (int r = 0; r < 16; ++r) acc[m][n][r] *= ratio;
        }
    }

    // ---- epilogue: C/D row = (r&3)+8*(r>>2)+4*(l>>5), col = l&31 ----
    #pragma unroll
    for (int m = 0; m < 2; ++m) {
        #pragma unroll
        for (int n = 0; n < 2; ++n) {
            #pragma unroll
            for (int r = 0; r < 16; ++r) {
                const int oc   = 32 * m + (r & 3) + ((r >> 2) << 3) + ((l >> 5) << 2);
                const int colp = 32 * n + (l & 31);
                const size_t off = (size_t)oc * NPIX + (size_t)(r0 + w) * 64 + colp;
                float v = acc[m][n][r];
                if (MODE == 0) {
                    v = lrelu(v + bptr0[oc]);
                    ((u16*)outbase)[off] = f2bf(v);
                } else if (MODE == 1) {
                    v = v * g1 + g0 * bptr0[oc] + g1 * bptr1[oc];
                    ((u16*)outbase)[off] = f2bf(v);
                } else {
                    ((float*)outbase)[off] = v + bptr0[oc];
                }
            }
        }
    }
}

// ---------------------------------------------------------------------------
extern "C" void kernel_launch(void* const* d_in, const int* in_sizes, int n_in,
                              void* d_out, int out_size, void* d_ws, size_t ws_size,
                              hipStream_t stream)
{
    const float* x_rgb  = (const float*)d_in[0];
    const float* x_ir   = (const float*)d_in[1];
    const float* n_rgb  = (const float*)d_in[2];
    const float* n_ir   = (const float*)d_in[3];
    const float* wg_rgb = (const float*)d_in[4];
    const float* wn_rgb = (const float*)d_in[5];
    const float* wg_ir  = (const float*)d_in[6];
    const float* wn_ir  = (const float*)d_in[7];
    const float* We1    = (const float*)d_in[8];
    const float* be1    = (const float*)d_in[9];
    const float* We2    = (const float*)d_in[10];
    const float* be2    = (const float*)d_in[11];
    const float* Wr     = (const float*)d_in[12];
    const float* brb    = (const float*)d_in[13];
    float* out = (float*)d_out;

    // workspace layout (bytes):
    //   sel @ 0 (512 B) | gv @ 512 (512 B)
    //   A1 @ 1024 (589824 B) | A2 @ 590848 (589824 B) | Ar @ 1180672 (147456 B)
    //   h  @ 1328128 (67108864 B) | obr @ 68436992 (33554432 B)
    //   gating partials alias the h region (h written only after gating done).
    char* ws = (char*)d_ws;
    int*   sel = (int*)(ws + 0);
    float* gv  = (float*)(ws + 512);
    u16* A1  = (u16*)(ws + 1024);
    u16* A2  = (u16*)(ws + 590848);
    u16* Ar  = (u16*)(ws + 1180672);
    u16* h   = (u16*)(ws + 1328128);
    u16* obr = (u16*)(ws + 68436992);
    float* partial = (float*)(ws + 1328128);   // 64*32*8 f32 = 64 KB, inside h

    prep_kernel<<<2592, 256, 0, stream>>>(We1, We2, Wr, A1, A2, Ar);
    gating_partial<<<dim3(64, 32), 256, 0, stream>>>(x_rgb, x_ir,
                                                     wg_rgb, wn_rgb, wg_ir, wn_ir,
                                                     partial);
    gating_final<<<64, 256, 0, stream>>>(partial, n_rgb, n_ir, sel, gv);

    conv_mfma<0><<<dim3(128, 16), 256, 0, stream>>>(x_rgb, x_ir, A1, be1, sel, gv, h);
    conv_mfma<1><<<dim3(64, 16),  256, 0, stream>>>(h, nullptr, A2, be2, sel, gv, obr);
    conv_mfma<2><<<dim3(32, 16),  256, 0, stream>>>(obr, nullptr, Ar, brb, sel, gv, out);
}